// Round 2
// baseline (640.004 us; speedup 1.0000x reference)
//
#include <hip/hip_runtime.h>

// ---------------------------------------------------------------------------
// DistributionShiftGAT: 3-layer GAT on MI355X (gfx950).
// R13: XCD-sliced aggregation, group-per-node form. R12 proved slicing hits
//      the traffic floor (FETCH 241->30.7MB) but 8x wave count + cross-group
//      reduce tripled VALU time (75->126us, VALUBusy 79%). R13 keeps the
//      slicing and restores wave efficiency: each 8-lane group owns one
//      node's 128B slice (8 nodes/wave, no shuffles, overhead back to 1x).
//      Divergence killed by degree-bucketed node ordering (counting sort
//      folded into CSR build: 512-bin hist in scan_final + 1 small scan +
//      scatter in scatter_kernel). Slice rotated per node ((s+n)&7) to
//      spread L2 sets while preserving the XCD partition. GEMMs unchanged.
// ---------------------------------------------------------------------------

#define NEG_SLOPE 0.2f

typedef __attribute__((ext_vector_type(8))) short short8;
typedef __attribute__((ext_vector_type(4))) float floatx4;
typedef __attribute__((ext_vector_type(4))) unsigned uintx4;

static __device__ __forceinline__ unsigned short f2bf(float f) {
    unsigned u = __float_as_uint(f);
    u = u + 0x7FFFu + ((u >> 16) & 1u);      // RNE
    return (unsigned short)(u >> 16);
}
static __device__ __forceinline__ float bf2f_lo(unsigned u) {
    return __uint_as_float(u << 16);
}
static __device__ __forceinline__ float bf2f_hi(unsigned u) {
    return __uint_as_float(u & 0xFFFF0000u);
}

// async global->LDS, 16B per lane; LDS fills base + lane*16 (wave-uniform base)
static __device__ __forceinline__ void async_copy16(const void* g, void* l) {
    __builtin_amdgcn_global_load_lds(
        (const __attribute__((address_space(1))) unsigned int*)g,
        (__attribute__((address_space(3))) unsigned int*)l, 16, 0, 0);
}

// ---------------- fused prep (x cast + W transposes) + edge histogram -------
// cursor (and dhist right after it) must be zeroed before this kernel.

__global__ __launch_bounds__(256)
void prep_hist_kernel(const float* __restrict__ x, unsigned short* __restrict__ x_bf,
                      const float* __restrict__ W1, unsigned short* __restrict__ W1T,
                      const float* __restrict__ W2, unsigned short* __restrict__ W2T,
                      const float* __restrict__ W3, unsigned short* __restrict__ W3T,
                      const int* __restrict__ ei, int* cursor, int n4, int E) {
    int i = blockIdx.x * 256 + threadIdx.x;
    if (i < n4) {
        float4 v = ((const float4*)x)[i];
        ushort4 o;
        o.x = f2bf(v.x); o.y = f2bf(v.y); o.z = f2bf(v.z); o.w = f2bf(v.w);
        ((ushort4*)x_bf)[i] = o;
        return;
    }
    int j = i - n4;
    if (j < 256 * 512) {                       // W1 [256,512] -> W1T [512,256]
        int k = j >> 9, n = j & 511;
        W1T[(size_t)n * 256 + k] = f2bf(W1[j]);
        return;
    }
    j -= 256 * 512;
    if (j < 512 * 512) {                       // W2 [512,512] -> W2T [512,512]
        int k = j >> 9, n = j & 511;
        W2T[(size_t)n * 512 + k] = f2bf(W2[j]);
        return;
    }
    j -= 512 * 512;
    if (j < 512 * 128) {                       // W3 [512,128] -> W3T [128,512]
        int k = j >> 7, n = j & 127;
        W3T[(size_t)n * 512 + k] = f2bf(W3[j]);
        return;
    }
    j -= 512 * 128;
    if (j < E) atomicAdd(&cursor[ei[E + j]], 1);   // histogram of dst
}

// ---------------- CSR scan (self-loops folded: row_ptr[i]=edge_prefix+i) ----

__global__ __launch_bounds__(1024)
void scan_bsum_kernel(const int* __restrict__ cursor, int* __restrict__ bsum, int N) {
    __shared__ int wsum[16];
    int tid = threadIdx.x, lane = tid & 63, w = tid >> 6;
    int i = blockIdx.x * 1024 + tid;
    int v = (i < N) ? cursor[i] : 0;
    #pragma unroll
    for (int off = 32; off; off >>= 1) v += __shfl_xor(v, off, 64);
    if (lane == 0) wsum[w] = v;
    __syncthreads();
    if (tid == 0) {
        int t = 0;
        #pragma unroll
        for (int k = 0; k < 16; ++k) t += wsum[k];
        bsum[blockIdx.x] = t;
    }
}

__global__ __launch_bounds__(1024)
void scan_final_kernel(int* __restrict__ cursor, const int* __restrict__ bsum,
                       int* __restrict__ row_ptr, int* __restrict__ dhist,
                       int N, int NB) {
    __shared__ int wsum[16];
    __shared__ int boff_sh;
    int tid = threadIdx.x, lane = tid & 63, w = tid >> 6;
    if (w == 0) {
        int bv = (lane < NB) ? bsum[lane] : 0;
        int bx = bv;
        #pragma unroll
        for (int off = 1; off < 64; off <<= 1) {
            int t = __shfl_up(bx, off, 64);
            if (lane >= off) bx += t;
        }
        if (lane == blockIdx.x) boff_sh = bx - bv;       // exclusive prefix
        if (blockIdx.x == 0 && lane == 63) row_ptr[N] = bx + N;  // +N self-loops
    }
    int i = blockIdx.x * 1024 + tid;
    int v = (i < N) ? cursor[i] : 0;
    if (i < N) atomicAdd(&dhist[v < 511 ? v : 511], 1);  // degree histogram
    int x = v;
    #pragma unroll
    for (int off = 1; off < 64; off <<= 1) {
        int t = __shfl_up(x, off, 64);
        if (lane >= off) x += t;
    }
    if (lane == 63) wsum[w] = x;
    __syncthreads();
    if (w == 0 && lane < 16) {
        int y = wsum[lane];
        #pragma unroll
        for (int off = 1; off < 16; off <<= 1) {
            int t = __shfl_up(y, off, 64);
            if (lane >= off) y += t;
        }
        wsum[lane] = y;
    }
    __syncthreads();
    int woff = (w == 0) ? 0 : wsum[w - 1];
    int ex = boff_sh + woff + x - v + i;     // + i = self-loop slots
    if (i < N) { row_ptr[i] = ex; cursor[i] = ex; }
}

// exclusive prefix over the 512-bin degree histogram (1 block, 512 threads)
__global__ __launch_bounds__(512)
void deg_scan_kernel(const int* __restrict__ dhist, int* __restrict__ dcur) {
    __shared__ int ws[8];
    int tid = threadIdx.x, lane = tid & 63, w = tid >> 6;
    int v = dhist[tid];
    int x = v;
    #pragma unroll
    for (int off = 1; off < 64; off <<= 1) {
        int t = __shfl_up(x, off, 64);
        if (lane >= off) x += t;
    }
    if (lane == 63) ws[w] = x;
    __syncthreads();
    if (w == 0 && lane < 8) {
        int y = ws[lane];
        #pragma unroll
        for (int off = 1; off < 8; off <<= 1) {
            int t = __shfl_up(y, off, 64);
            if (lane >= off) y += t;
        }
        ws[lane] = y;
    }
    __syncthreads();
    int woff = (w == 0) ? 0 : ws[w - 1];
    dcur[tid] = woff + x - v;                // exclusive prefix
}

__global__ __launch_bounds__(256)
void scatter_kernel(const int* __restrict__ ei, int* cursor,
                    int* __restrict__ csr_src, const int* __restrict__ row_ptr,
                    int* __restrict__ dcur, int* __restrict__ node_order,
                    int E, int N) {
    int i = blockIdx.x * 256 + threadIdx.x;
    if (i < E) {
        int s = ei[i], d = ei[E + i];
        int pos = atomicAdd(&cursor[d], 1);
        csr_src[pos] = s;
    } else if (i < E + N) {
        int n = i - E;
        int pos = atomicAdd(&cursor[n], 1);
        csr_src[pos] = n;                // self loop
    } else if (i < E + 2 * N) {
        int n = i - E - N;
        int d = row_ptr[n + 1] - row_ptr[n] - 1;   // edge-degree (matches dhist)
        int pos = atomicAdd(&dcur[d < 511 ? d : 511], 1);
        node_order[pos] = n;             // degree-bucketed processing order
    }
}

// ---------------- bf16 MFMA GEMM + fused attention dots ----------------
// C[M,Nn]bf16 = A[M,K]bf16 @ BT[Nn,K]^T. TMxTN tile, BK=64, 8 waves (512 thr),
// 64x64 wave tiles. A+B staged into one LDS buffer (rows 0..TM-1 = A,
// TM..TM+TN-1 = B) via global_load_lds 16B/lane; phys seg = seg ^ (row&7)
// keeps both staging and b128 frag reads bank-minimal.
// Epilogue computes a_src/a_dst (layout [H][N] for XCD-sliced agg).

template<int TM, int TN>
__global__ __launch_bounds__(512)
void mfma_gemm_kernel(const unsigned short* __restrict__ A,
                      const unsigned short* __restrict__ BT,
                      unsigned short* __restrict__ C,
                      const float* __restrict__ att_src,
                      const float* __restrict__ att_dst,
                      float* __restrict__ a_srcO, float* __restrict__ a_dstO,
                      int H, int M, int Nn, int K) {
    constexpr int NH = TN / 128;               // heads per block
    __shared__ unsigned short buf[(TM + TN) * 64];    // 48 KB
    __shared__ float psum[TN / 64][TM];
    __shared__ float pdsum[TN / 64][TM];
    const int tid = threadIdx.x;
    const int m0 = blockIdx.y * TM;
    const int n0 = blockIdx.x * TN;
    const int head_base = blockIdx.x * NH;
    const int lane = tid & 63, wave = tid >> 6;        // wave 0..7
    const int wm = (wave & (TM / 64 - 1)) * 64;
    const int wn = (wave / (TM / 64)) * 64;
    const int quad = lane >> 4, rr = lane & 15;

    // staging: 8 waves x 6 insts x 8 rows = 384 rows (TM A-rows + TN B-rows)
    const int srow = lane >> 3;                // row within 8-row group
    const int sseg = (lane & 7) ^ srow;        // logical 8-elem seg to fetch
    const unsigned short* gptr[6];
    unsigned short* lptr[6];
    #pragma unroll
    for (int j = 0; j < 6; ++j) {
        int base_row = wave * 48 + j * 8;      // multiple of 8; A/B uniform
        lptr[j] = buf + base_row * 64;
        if (base_row < TM) {
            int gr = min(m0 + base_row + srow, M - 1);
            gptr[j] = A + (size_t)gr * K;
        } else {
            int gr = n0 + (base_row - TM) + srow;
            gptr[j] = BT + (size_t)gr * K;
        }
    }

    floatx4 acc[4][4] = {};

    for (int k0 = 0; k0 < K; k0 += 64) {
        #pragma unroll
        for (int j = 0; j < 6; ++j)
            async_copy16(gptr[j] + k0 + sseg * 8, lptr[j]);
        __syncthreads();

        #pragma unroll
        for (int k32 = 0; k32 < 2; ++k32) {
            short8 af[4], bf[4];
            #pragma unroll
            for (int mi = 0; mi < 4; ++mi) {
                int row = wm + mi * 16 + rr;
                int phys = (k32 * 4 + quad) ^ (rr & 7);
                af[mi] = *(const short8*)(buf + row * 64 + phys * 8);
            }
            #pragma unroll
            for (int ni = 0; ni < 4; ++ni) {
                int row = TM + wn + ni * 16 + rr;
                int phys = (k32 * 4 + quad) ^ (rr & 7);
                bf[ni] = *(const short8*)(buf + row * 64 + phys * 8);
            }
            #pragma unroll
            for (int mi = 0; mi < 4; ++mi)
                #pragma unroll
                for (int ni = 0; ni < 4; ++ni)
                    acc[mi][ni] = __builtin_amdgcn_mfma_f32_16x16x32_bf16(
                        af[mi], bf[ni], acc[mi][ni], 0, 0, 0);
        }
        __syncthreads();
    }

    // ---- h store (bf16), C/D layout: col=lane&15, row=quad*4+reg ----
    #pragma unroll
    for (int mi = 0; mi < 4; ++mi) {
        #pragma unroll
        for (int ni = 0; ni < 4; ++ni) {
            int col = n0 + wn + ni * 16 + rr;
            #pragma unroll
            for (int r = 0; r < 4; ++r) {
                int row = m0 + wm + mi * 16 + quad * 4 + r;
                if (row < M) C[(size_t)row * Nn + col] = f2bf(acc[mi][ni][r]);
            }
        }
    }

    // ---- fused attention dots (per covered head) ----
    float ats[4], atd[4];
    #pragma unroll
    for (int ni = 0; ni < 4; ++ni) {
        int cc = wn + ni * 16;                  // col within block tile
        int h = head_base + (cc >> 7);
        int c = (cc + rr) & 127;                // channel within head
        ats[ni] = att_src[h * 128 + c];
        atd[ni] = att_dst[h * 128 + c];
    }
    const int wg = wn >> 6;                     // wave column group
    #pragma unroll
    for (int mi = 0; mi < 4; ++mi) {
        #pragma unroll
        for (int r = 0; r < 4; ++r) {
            float ps = 0.f, pd = 0.f;
            #pragma unroll
            for (int ni = 0; ni < 4; ++ni) {
                ps += ats[ni] * acc[mi][ni][r];
                pd += atd[ni] * acc[mi][ni][r];
            }
            #pragma unroll
            for (int off = 1; off < 16; off <<= 1) {
                ps += __shfl_xor(ps, off, 64);
                pd += __shfl_xor(pd, off, 64);
            }
            if (rr == 0) {
                int row = wm + mi * 16 + quad * 4 + r;   // local row
                psum[wg][row] = ps;
                pdsum[wg][row] = pd;
            }
        }
    }
    __syncthreads();
    if (tid < NH * TM) {
        int h = tid / TM, r = tid % TM;
        int gr = m0 + r;
        if (gr < M) {
            // [H][N] layout: slice-local reads in agg touch only head h's row
            a_srcO[(size_t)(head_base + h) * M + gr] = psum[2 * h][r] + psum[2 * h + 1][r];
            a_dstO[(size_t)(head_base + h) * M + gr] = pdsum[2 * h][r] + pdsum[2 * h + 1][r];
        }
    }
}

// ---------------- XCD-sliced group-per-node softmax + aggregation -----------
// 8-lane GROUP owns one (node, slice): lane l holds 4 uints (16B) of the
// node's 128B slice; the group walks the node's edge list sequentially with
// a depth-4 pipelined gather (R11's proven pattern). 8 nodes per wave, zero
// shuffles (each lane's dacc is the full softmax denom; acc is lane-owned).
// Nodes processed in degree-bucketed order (node_order) -> the 8 groups of a
// wave have near-equal degree -> minimal exec-mask waste on the maxd loop.
// Slice pinned to XCD via blockIdx%NSLICE (round-robin dispatch), rotated per
// node ((s+n)&mask) to spread L2 sets; per-XCD hfeat footprint = 3.84MB < L2.
// csr_src non-temporal (stream), outputs non-temporal (protect residency).

template<int F, int H, int NSLICE, bool RELU, bool BF16OUT>
__global__ __launch_bounds__(256)
void agg_kernel(const unsigned* __restrict__ hfeat, const float* __restrict__ a_src,
                const float* __restrict__ a_dst, const int* __restrict__ row_ptr,
                const int* __restrict__ csr_src, const int* __restrict__ node_order,
                const float* __restrict__ bias, void* __restrict__ out_v, int N) {
    constexpr int RU = F / 2;                // uints per feature row
    constexpr int SU = RU / NSLICE;          // uints per slice (32 -> 128B)
    constexpr int GS = SU / 4;               // lanes per group (8)
    constexpr int GPW = 64 / GS;             // nodes per wave (8)
    constexpr int FS = F / NSLICE;           // feats per slice (64)
    static_assert(GS == 8, "group size must be 8");
    const int lane = threadIdx.x & 63, wave = threadIdx.x >> 6;
    const int s0 = blockIdx.x % NSLICE;      // slice class -> XCD affinity
    const int g = lane >> 3, l = lane & 7;
    int ni = ((blockIdx.x / NSLICE) * 4 + wave) * GPW + g;
    ni = ni < N ? ni : N - 1;                // dup tail: same bytes, benign
    const int node = node_order[ni];
    const int s = (s0 + node) & (NSLICE - 1);      // rotated slice
    const int begin = row_ptr[node];
    const int deg = row_ptr[node + 1] - begin;     // >= 1 (self-loop)
    const int h = (s * FS) / (F / H);
    const float adst = a_dst[(size_t)h * N + node];
    const unsigned* __restrict__ sbase = hfeat + (size_t)s * SU + l * 4;
    const float* __restrict__ asrc_h = a_src + (size_t)h * N;
    const int* __restrict__ crow = csr_src + begin;

    int maxd = deg;                          // max degree across the 8 groups
    #pragma unroll
    for (int off = 8; off < 64; off <<= 1) {
        int t = __shfl_xor(maxd, off, 64);
        maxd = t > maxd ? t : maxd;
    }

    float acc[8] = {};
    float dacc = 0.f;
    uintx4 u0, u1, u2, u3;
    float av0, av1, av2, av3;

#define LOADSLOT(idx, U, AV)                                                  \
    {                                                                         \
        int e_ = (idx) < deg ? (idx) : deg - 1;                               \
        int src_ = __builtin_nontemporal_load(crow + e_);                     \
        U = *(const uintx4*)(sbase + (size_t)src_ * RU);                      \
        AV = asrc_h[src_];                                                    \
    }

#define CONSUME(idx, U, AV)                                                   \
    {                                                                         \
        float e_ = AV + adst;                                                 \
        e_ = fmaxf(e_, NEG_SLOPE * e_);                                       \
        float ex_ = ((idx) < deg) ? __expf(e_) : 0.f;                         \
        dacc += ex_;                                                          \
        _Pragma("unroll")                                                     \
        for (int q_ = 0; q_ < 4; ++q_) {                                      \
            acc[2 * q_]     += ex_ * bf2f_lo(U[q_]);                          \
            acc[2 * q_ + 1] += ex_ * bf2f_hi(U[q_]);                          \
        }                                                                     \
    }

    LOADSLOT(0, u0, av0);
    LOADSLOT(1, u1, av1);
    LOADSLOT(2, u2, av2);
    LOADSLOT(3, u3, av3);
    int i = 0;
    for (; i + 4 < maxd; i += 4) {
        CONSUME(i,     u0, av0); LOADSLOT(i + 4, u0, av0);
        CONSUME(i + 1, u1, av1); LOADSLOT(i + 5, u1, av1);
        CONSUME(i + 2, u2, av2); LOADSLOT(i + 6, u2, av2);
        CONSUME(i + 3, u3, av3); LOADSLOT(i + 7, u3, av3);
    }
    CONSUME(i,     u0, av0);
    CONSUME(i + 1, u1, av1);
    CONSUME(i + 2, u2, av2);
    CONSUME(i + 3, u3, av3);
#undef LOADSLOT
#undef CONSUME

    // each lane of a group already holds the full denom and its 8 features
    float inv = 1.f / dacc;
    const int cb = s * FS + l * 8;           // feature base of this lane
    float v[8];
    #pragma unroll
    for (int j = 0; j < 8; ++j) {
        float t = acc[j] * inv + bias[cb + j];
        v[j] = RELU ? fmaxf(t, 0.f) : t;
    }
    if (BF16OUT) {
        uintx4 pk;
        #pragma unroll
        for (int q = 0; q < 4; ++q)
            pk[q] = (unsigned)f2bf(v[2 * q]) | ((unsigned)f2bf(v[2 * q + 1]) << 16);
        __builtin_nontemporal_store(pk,
            (uintx4*)((unsigned*)out_v + (size_t)node * RU + s * SU + l * 4));
    } else {
        floatx4 o0 = {v[0], v[1], v[2], v[3]};
        floatx4 o1 = {v[4], v[5], v[6], v[7]};
        float* dst = (float*)out_v + (size_t)node * F + cb;
        __builtin_nontemporal_store(o0, (floatx4*)dst);
        __builtin_nontemporal_store(o1, (floatx4*)(dst + 4));
    }
}

// ---------------- host launch ----------------

extern "C" void kernel_launch(void* const* d_in, const int* in_sizes, int n_in,
                              void* d_out, int out_size, void* d_ws, size_t ws_size,
                              hipStream_t stream) {
    const float* x        = (const float*)d_in[0];
    const int*   ei       = (const int*)  d_in[1];
    const float* W1       = (const float*)d_in[2];
    const float* att_src1 = (const float*)d_in[3];
    const float* att_dst1 = (const float*)d_in[4];
    const float* b1       = (const float*)d_in[5];
    const float* W2       = (const float*)d_in[6];
    const float* att_src2 = (const float*)d_in[7];
    const float* att_dst2 = (const float*)d_in[8];
    const float* b2       = (const float*)d_in[9];
    const float* W3       = (const float*)d_in[10];
    const float* att_src3 = (const float*)d_in[11];
    const float* att_dst3 = (const float*)d_in[12];
    const float* b3       = (const float*)d_in[13];

    const int IN_FEATS = 256;
    const int N = in_sizes[0] / IN_FEATS;   // 30000
    const int E = in_sizes[1] / 2;          // 480000
    const int ET = E + N;
    const int NB = (N + 1023) / 1024;       // scan blocks (30)

    // workspace layout
    char* p = (char*)d_ws;
    unsigned short* h_bf    = (unsigned short*)p; p += (size_t)N * 512 * sizeof(unsigned short);
    unsigned short* act_bf  = (unsigned short*)p; p += (size_t)N * 512 * sizeof(unsigned short);
    unsigned short* x_bf    = (unsigned short*)p; p += (size_t)N * 256 * sizeof(unsigned short);
    float*          a_src   = (float*)p;          p += (size_t)N * 4 * sizeof(float);
    float*          a_dst   = (float*)p;          p += (size_t)N * 4 * sizeof(float);
    unsigned short* W1T     = (unsigned short*)p; p += (size_t)512 * 256 * sizeof(unsigned short);
    unsigned short* W2T     = (unsigned short*)p; p += (size_t)512 * 512 * sizeof(unsigned short);
    unsigned short* W3T     = (unsigned short*)p; p += (size_t)128 * 512 * sizeof(unsigned short);
    int*            row_ptr = (int*)p;            p += ((size_t)N + 16) * sizeof(int);
    int*            cursor  = (int*)p;            p += (size_t)N * sizeof(int);
    int*            dhist   = (int*)p;            p += 512 * sizeof(int);
    int*            dcur    = (int*)p;            p += 512 * sizeof(int);
    int*            node_order = (int*)p;         p += (size_t)N * sizeof(int);
    int*            bsum    = (int*)p;            p += 64 * sizeof(int);
    int*            csr_src = (int*)p;            p += (size_t)ET * sizeof(int);

    // ---- prep (x cast + W transposes + hist) + CSR build + degree sort ----
    hipMemsetAsync(cursor, 0, ((size_t)N + 512) * sizeof(int), stream);  // cursor + dhist
    {
        int n4 = N * 256 / 4;
        int total = n4 + 256 * 512 + 512 * 512 + 512 * 128 + E;
        prep_hist_kernel<<<(total + 255) / 256, 256, 0, stream>>>(
            x, x_bf, W1, W1T, W2, W2T, W3, W3T, ei, cursor, n4, E);
    }
    scan_bsum_kernel<<<NB, 1024, 0, stream>>>(cursor, bsum, N);
    scan_final_kernel<<<NB, 1024, 0, stream>>>(cursor, bsum, row_ptr, dhist, N, NB);
    deg_scan_kernel<<<1, 512, 0, stream>>>(dhist, dcur);
    scatter_kernel<<<(E + 2 * N + 255) / 256, 256, 0, stream>>>(
        ei, cursor, csr_src, row_ptr, dcur, node_order, E, N);

    const int MB128 = (N + 127) / 128;      // 235
    const int MB256 = (N + 255) / 256;      // 118
    const int NC32 = (N + 31) / 32;         // node chunks (32 nodes/block)

    // ---- Layer 1: 256 -> 4x128 concat + relu (h bf16) ----
    mfma_gemm_kernel<128, 256><<<dim3(2, MB128), 512, 0, stream>>>(x_bf, W1T, h_bf, att_src1, att_dst1, a_src, a_dst, 4, N, 512, 256);
    agg_kernel<512, 4, 8, true, true><<<8 * NC32, 256, 0, stream>>>((const unsigned*)h_bf, a_src, a_dst, row_ptr, csr_src, node_order, b1, act_bf, N);

    // ---- Layer 2: 512 -> 4x128 concat + relu (h bf16) ----
    mfma_gemm_kernel<128, 256><<<dim3(2, MB128), 512, 0, stream>>>(act_bf, W2T, h_bf, att_src2, att_dst2, a_src, a_dst, 4, N, 512, 512);
    agg_kernel<512, 4, 8, true, true><<<8 * NC32, 256, 0, stream>>>((const unsigned*)h_bf, a_src, a_dst, row_ptr, csr_src, node_order, b2, act_bf, N);

    // ---- Layer 3: 512 -> 1x128 (h bf16), fp32 out, no relu ----
    mfma_gemm_kernel<256, 128><<<dim3(1, MB256), 512, 0, stream>>>(act_bf, W3T, h_bf, att_src3, att_dst3, a_src, a_dst, 1, N, 128, 512);
    agg_kernel<128, 1, 2, false, false><<<2 * NC32, 256, 0, stream>>>((const unsigned*)h_bf, a_src, a_dst, row_ptr, csr_src, node_order, b3, d_out, N);
}

// Round 3
// 618.809 us; speedup vs baseline: 1.0343x; 1.0343x over previous
//
#include <hip/hip_runtime.h>

// ---------------------------------------------------------------------------
// DistributionShiftGAT: 3-layer GAT on MI355X (gfx950).
// R14: R13 group-per-node agg with the slice ROTATION REMOVED. R13's
//      s=(s0+node)&7 made each XCD touch all 8 slices (FETCH 315MB,
//      latency-bound on HBM gathers). Fixed s=s0 restores R12's proven
//      traffic floor (per-XCD working set 3.66MiB < 4MiB L2, FETCH =
//      compulsory 30.7MB) while keeping R13's wave efficiency (8-lane group
//      owns one node's 128B slice, zero shuffles, 30K waves).
//      Degree-bucketed node order kept (balances the maxd loop).
//      GEMMs / prep / CSR build unchanged.
// ---------------------------------------------------------------------------

#define NEG_SLOPE 0.2f

typedef __attribute__((ext_vector_type(8))) short short8;
typedef __attribute__((ext_vector_type(4))) float floatx4;
typedef __attribute__((ext_vector_type(4))) unsigned uintx4;

static __device__ __forceinline__ unsigned short f2bf(float f) {
    unsigned u = __float_as_uint(f);
    u = u + 0x7FFFu + ((u >> 16) & 1u);      // RNE
    return (unsigned short)(u >> 16);
}
static __device__ __forceinline__ float bf2f_lo(unsigned u) {
    return __uint_as_float(u << 16);
}
static __device__ __forceinline__ float bf2f_hi(unsigned u) {
    return __uint_as_float(u & 0xFFFF0000u);
}

// async global->LDS, 16B per lane; LDS fills base + lane*16 (wave-uniform base)
static __device__ __forceinline__ void async_copy16(const void* g, void* l) {
    __builtin_amdgcn_global_load_lds(
        (const __attribute__((address_space(1))) unsigned int*)g,
        (__attribute__((address_space(3))) unsigned int*)l, 16, 0, 0);
}

// ---------------- fused prep (x cast + W transposes) + edge histogram -------
// cursor (and dhist right after it) must be zeroed before this kernel.

__global__ __launch_bounds__(256)
void prep_hist_kernel(const float* __restrict__ x, unsigned short* __restrict__ x_bf,
                      const float* __restrict__ W1, unsigned short* __restrict__ W1T,
                      const float* __restrict__ W2, unsigned short* __restrict__ W2T,
                      const float* __restrict__ W3, unsigned short* __restrict__ W3T,
                      const int* __restrict__ ei, int* cursor, int n4, int E) {
    int i = blockIdx.x * 256 + threadIdx.x;
    if (i < n4) {
        float4 v = ((const float4*)x)[i];
        ushort4 o;
        o.x = f2bf(v.x); o.y = f2bf(v.y); o.z = f2bf(v.z); o.w = f2bf(v.w);
        ((ushort4*)x_bf)[i] = o;
        return;
    }
    int j = i - n4;
    if (j < 256 * 512) {                       // W1 [256,512] -> W1T [512,256]
        int k = j >> 9, n = j & 511;
        W1T[(size_t)n * 256 + k] = f2bf(W1[j]);
        return;
    }
    j -= 256 * 512;
    if (j < 512 * 512) {                       // W2 [512,512] -> W2T [512,512]
        int k = j >> 9, n = j & 511;
        W2T[(size_t)n * 512 + k] = f2bf(W2[j]);
        return;
    }
    j -= 512 * 512;
    if (j < 512 * 128) {                       // W3 [512,128] -> W3T [128,512]
        int k = j >> 7, n = j & 127;
        W3T[(size_t)n * 512 + k] = f2bf(W3[j]);
        return;
    }
    j -= 512 * 128;
    if (j < E) atomicAdd(&cursor[ei[E + j]], 1);   // histogram of dst
}

// ---------------- CSR scan (self-loops folded: row_ptr[i]=edge_prefix+i) ----

__global__ __launch_bounds__(1024)
void scan_bsum_kernel(const int* __restrict__ cursor, int* __restrict__ bsum, int N) {
    __shared__ int wsum[16];
    int tid = threadIdx.x, lane = tid & 63, w = tid >> 6;
    int i = blockIdx.x * 1024 + tid;
    int v = (i < N) ? cursor[i] : 0;
    #pragma unroll
    for (int off = 32; off; off >>= 1) v += __shfl_xor(v, off, 64);
    if (lane == 0) wsum[w] = v;
    __syncthreads();
    if (tid == 0) {
        int t = 0;
        #pragma unroll
        for (int k = 0; k < 16; ++k) t += wsum[k];
        bsum[blockIdx.x] = t;
    }
}

__global__ __launch_bounds__(1024)
void scan_final_kernel(int* __restrict__ cursor, const int* __restrict__ bsum,
                       int* __restrict__ row_ptr, int* __restrict__ dhist,
                       int N, int NB) {
    __shared__ int wsum[16];
    __shared__ int boff_sh;
    int tid = threadIdx.x, lane = tid & 63, w = tid >> 6;
    if (w == 0) {
        int bv = (lane < NB) ? bsum[lane] : 0;
        int bx = bv;
        #pragma unroll
        for (int off = 1; off < 64; off <<= 1) {
            int t = __shfl_up(bx, off, 64);
            if (lane >= off) bx += t;
        }
        if (lane == blockIdx.x) boff_sh = bx - bv;       // exclusive prefix
        if (blockIdx.x == 0 && lane == 63) row_ptr[N] = bx + N;  // +N self-loops
    }
    int i = blockIdx.x * 1024 + tid;
    int v = (i < N) ? cursor[i] : 0;
    if (i < N) atomicAdd(&dhist[v < 511 ? v : 511], 1);  // degree histogram
    int x = v;
    #pragma unroll
    for (int off = 1; off < 64; off <<= 1) {
        int t = __shfl_up(x, off, 64);
        if (lane >= off) x += t;
    }
    if (lane == 63) wsum[w] = x;
    __syncthreads();
    if (w == 0 && lane < 16) {
        int y = wsum[lane];
        #pragma unroll
        for (int off = 1; off < 16; off <<= 1) {
            int t = __shfl_up(y, off, 64);
            if (lane >= off) y += t;
        }
        wsum[lane] = y;
    }
    __syncthreads();
    int woff = (w == 0) ? 0 : wsum[w - 1];
    int ex = boff_sh + woff + x - v + i;     // + i = self-loop slots
    if (i < N) { row_ptr[i] = ex; cursor[i] = ex; }
}

// exclusive prefix over the 512-bin degree histogram (1 block, 512 threads)
__global__ __launch_bounds__(512)
void deg_scan_kernel(const int* __restrict__ dhist, int* __restrict__ dcur) {
    __shared__ int ws[8];
    int tid = threadIdx.x, lane = tid & 63, w = tid >> 6;
    int v = dhist[tid];
    int x = v;
    #pragma unroll
    for (int off = 1; off < 64; off <<= 1) {
        int t = __shfl_up(x, off, 64);
        if (lane >= off) x += t;
    }
    if (lane == 63) ws[w] = x;
    __syncthreads();
    if (w == 0 && lane < 8) {
        int y = ws[lane];
        #pragma unroll
        for (int off = 1; off < 8; off <<= 1) {
            int t = __shfl_up(y, off, 64);
            if (lane >= off) y += t;
        }
        ws[lane] = y;
    }
    __syncthreads();
    int woff = (w == 0) ? 0 : ws[w - 1];
    dcur[tid] = woff + x - v;                // exclusive prefix
}

__global__ __launch_bounds__(256)
void scatter_kernel(const int* __restrict__ ei, int* cursor,
                    int* __restrict__ csr_src, const int* __restrict__ row_ptr,
                    int* __restrict__ dcur, int* __restrict__ node_order,
                    int E, int N) {
    int i = blockIdx.x * 256 + threadIdx.x;
    if (i < E) {
        int s = ei[i], d = ei[E + i];
        int pos = atomicAdd(&cursor[d], 1);
        csr_src[pos] = s;
    } else if (i < E + N) {
        int n = i - E;
        int pos = atomicAdd(&cursor[n], 1);
        csr_src[pos] = n;                // self loop
    } else if (i < E + 2 * N) {
        int n = i - E - N;
        int d = row_ptr[n + 1] - row_ptr[n] - 1;   // edge-degree (matches dhist)
        int pos = atomicAdd(&dcur[d < 511 ? d : 511], 1);
        node_order[pos] = n;             // degree-bucketed processing order
    }
}

// ---------------- bf16 MFMA GEMM + fused attention dots ----------------
// C[M,Nn]bf16 = A[M,K]bf16 @ BT[Nn,K]^T. TMxTN tile, BK=64, 8 waves (512 thr),
// 64x64 wave tiles. A+B staged into one LDS buffer (rows 0..TM-1 = A,
// TM..TM+TN-1 = B) via global_load_lds 16B/lane; phys seg = seg ^ (row&7)
// keeps both staging and b128 frag reads bank-minimal.
// Epilogue computes a_src/a_dst (layout [H][N] for XCD-sliced agg).

template<int TM, int TN>
__global__ __launch_bounds__(512)
void mfma_gemm_kernel(const unsigned short* __restrict__ A,
                      const unsigned short* __restrict__ BT,
                      unsigned short* __restrict__ C,
                      const float* __restrict__ att_src,
                      const float* __restrict__ att_dst,
                      float* __restrict__ a_srcO, float* __restrict__ a_dstO,
                      int H, int M, int Nn, int K) {
    constexpr int NH = TN / 128;               // heads per block
    __shared__ unsigned short buf[(TM + TN) * 64];    // 48 KB
    __shared__ float psum[TN / 64][TM];
    __shared__ float pdsum[TN / 64][TM];
    const int tid = threadIdx.x;
    const int m0 = blockIdx.y * TM;
    const int n0 = blockIdx.x * TN;
    const int head_base = blockIdx.x * NH;
    const int lane = tid & 63, wave = tid >> 6;        // wave 0..7
    const int wm = (wave & (TM / 64 - 1)) * 64;
    const int wn = (wave / (TM / 64)) * 64;
    const int quad = lane >> 4, rr = lane & 15;

    // staging: 8 waves x 6 insts x 8 rows = 384 rows (TM A-rows + TN B-rows)
    const int srow = lane >> 3;                // row within 8-row group
    const int sseg = (lane & 7) ^ srow;        // logical 8-elem seg to fetch
    const unsigned short* gptr[6];
    unsigned short* lptr[6];
    #pragma unroll
    for (int j = 0; j < 6; ++j) {
        int base_row = wave * 48 + j * 8;      // multiple of 8; A/B uniform
        lptr[j] = buf + base_row * 64;
        if (base_row < TM) {
            int gr = min(m0 + base_row + srow, M - 1);
            gptr[j] = A + (size_t)gr * K;
        } else {
            int gr = n0 + (base_row - TM) + srow;
            gptr[j] = BT + (size_t)gr * K;
        }
    }

    floatx4 acc[4][4] = {};

    for (int k0 = 0; k0 < K; k0 += 64) {
        #pragma unroll
        for (int j = 0; j < 6; ++j)
            async_copy16(gptr[j] + k0 + sseg * 8, lptr[j]);
        __syncthreads();

        #pragma unroll
        for (int k32 = 0; k32 < 2; ++k32) {
            short8 af[4], bf[4];
            #pragma unroll
            for (int mi = 0; mi < 4; ++mi) {
                int row = wm + mi * 16 + rr;
                int phys = (k32 * 4 + quad) ^ (rr & 7);
                af[mi] = *(const short8*)(buf + row * 64 + phys * 8);
            }
            #pragma unroll
            for (int ni = 0; ni < 4; ++ni) {
                int row = TM + wn + ni * 16 + rr;
                int phys = (k32 * 4 + quad) ^ (rr & 7);
                bf[ni] = *(const short8*)(buf + row * 64 + phys * 8);
            }
            #pragma unroll
            for (int mi = 0; mi < 4; ++mi)
                #pragma unroll
                for (int ni = 0; ni < 4; ++ni)
                    acc[mi][ni] = __builtin_amdgcn_mfma_f32_16x16x32_bf16(
                        af[mi], bf[ni], acc[mi][ni], 0, 0, 0);
        }
        __syncthreads();
    }

    // ---- h store (bf16), C/D layout: col=lane&15, row=quad*4+reg ----
    #pragma unroll
    for (int mi = 0; mi < 4; ++mi) {
        #pragma unroll
        for (int ni = 0; ni < 4; ++ni) {
            int col = n0 + wn + ni * 16 + rr;
            #pragma unroll
            for (int r = 0; r < 4; ++r) {
                int row = m0 + wm + mi * 16 + quad * 4 + r;
                if (row < M) C[(size_t)row * Nn + col] = f2bf(acc[mi][ni][r]);
            }
        }
    }

    // ---- fused attention dots (per covered head) ----
    float ats[4], atd[4];
    #pragma unroll
    for (int ni = 0; ni < 4; ++ni) {
        int cc = wn + ni * 16;                  // col within block tile
        int h = head_base + (cc >> 7);
        int c = (cc + rr) & 127;                // channel within head
        ats[ni] = att_src[h * 128 + c];
        atd[ni] = att_dst[h * 128 + c];
    }
    const int wg = wn >> 6;                     // wave column group
    #pragma unroll
    for (int mi = 0; mi < 4; ++mi) {
        #pragma unroll
        for (int r = 0; r < 4; ++r) {
            float ps = 0.f, pd = 0.f;
            #pragma unroll
            for (int ni = 0; ni < 4; ++ni) {
                ps += ats[ni] * acc[mi][ni][r];
                pd += atd[ni] * acc[mi][ni][r];
            }
            #pragma unroll
            for (int off = 1; off < 16; off <<= 1) {
                ps += __shfl_xor(ps, off, 64);
                pd += __shfl_xor(pd, off, 64);
            }
            if (rr == 0) {
                int row = wm + mi * 16 + quad * 4 + r;   // local row
                psum[wg][row] = ps;
                pdsum[wg][row] = pd;
            }
        }
    }
    __syncthreads();
    if (tid < NH * TM) {
        int h = tid / TM, r = tid % TM;
        int gr = m0 + r;
        if (gr < M) {
            // [H][N] layout: slice-local reads in agg touch only head h's row
            a_srcO[(size_t)(head_base + h) * M + gr] = psum[2 * h][r] + psum[2 * h + 1][r];
            a_dstO[(size_t)(head_base + h) * M + gr] = pdsum[2 * h][r] + pdsum[2 * h + 1][r];
        }
    }
}

// ---------------- XCD-sliced group-per-node softmax + aggregation -----------
// 8-lane GROUP owns one (node, slice): lane l holds 4 uints (16B) of the
// node's 128B slice; the group walks the node's edge list sequentially with
// a depth-4 pipelined gather. 8 nodes per wave, zero shuffles.
// Slice s = blockIdx.x % NSLICE, FIXED per block -> round-robin dispatch pins
// slice s to XCD s; per-XCD hfeat footprint = N*128B = 3.66MiB < 4MiB L2
// (R12-proven: FETCH = compulsory table size, near-perfect L2 hit).
// Nodes processed in degree-bucketed order -> the 8 groups of a wave have
// near-equal degree -> minimal exec-mask waste on the maxd loop.
// csr_src non-temporal (stream), outputs non-temporal (protect residency).

template<int F, int H, int NSLICE, bool RELU, bool BF16OUT>
__global__ __launch_bounds__(256)
void agg_kernel(const unsigned* __restrict__ hfeat, const float* __restrict__ a_src,
                const float* __restrict__ a_dst, const int* __restrict__ row_ptr,
                const int* __restrict__ csr_src, const int* __restrict__ node_order,
                const float* __restrict__ bias, void* __restrict__ out_v, int N) {
    constexpr int RU = F / 2;                // uints per feature row
    constexpr int SU = RU / NSLICE;          // uints per slice (32 -> 128B)
    constexpr int GS = SU / 4;               // lanes per group (8)
    constexpr int GPW = 64 / GS;             // nodes per wave (8)
    constexpr int FS = F / NSLICE;           // feats per slice (64)
    static_assert(GS == 8, "group size must be 8");
    const int lane = threadIdx.x & 63, wave = threadIdx.x >> 6;
    const int s = blockIdx.x % NSLICE;       // FIXED slice -> XCD affinity
    const int g = lane >> 3, l = lane & 7;
    int ni = ((blockIdx.x / NSLICE) * 4 + wave) * GPW + g;
    ni = ni < N ? ni : N - 1;                // dup tail: same bytes, benign
    const int node = node_order[ni];
    const int begin = row_ptr[node];
    const int deg = row_ptr[node + 1] - begin;     // >= 1 (self-loop)
    const int h = (s * FS) / (F / H);
    const float adst = a_dst[(size_t)h * N + node];
    const unsigned* __restrict__ sbase = hfeat + (size_t)s * SU + l * 4;
    const float* __restrict__ asrc_h = a_src + (size_t)h * N;
    const int* __restrict__ crow = csr_src + begin;

    int maxd = deg;                          // max degree across the 8 groups
    #pragma unroll
    for (int off = 8; off < 64; off <<= 1) {
        int t = __shfl_xor(maxd, off, 64);
        maxd = t > maxd ? t : maxd;
    }

    float acc[8] = {};
    float dacc = 0.f;
    uintx4 u0, u1, u2, u3;
    float av0, av1, av2, av3;

#define LOADSLOT(idx, U, AV)                                                  \
    {                                                                         \
        int e_ = (idx) < deg ? (idx) : deg - 1;                               \
        int src_ = __builtin_nontemporal_load(crow + e_);                     \
        U = *(const uintx4*)(sbase + (size_t)src_ * RU);                      \
        AV = asrc_h[src_];                                                    \
    }

#define CONSUME(idx, U, AV)                                                   \
    {                                                                         \
        float e_ = AV + adst;                                                 \
        e_ = fmaxf(e_, NEG_SLOPE * e_);                                       \
        float ex_ = ((idx) < deg) ? __expf(e_) : 0.f;                         \
        dacc += ex_;                                                          \
        _Pragma("unroll")                                                     \
        for (int q_ = 0; q_ < 4; ++q_) {                                      \
            acc[2 * q_]     += ex_ * bf2f_lo(U[q_]);                          \
            acc[2 * q_ + 1] += ex_ * bf2f_hi(U[q_]);                          \
        }                                                                     \
    }

    LOADSLOT(0, u0, av0);
    LOADSLOT(1, u1, av1);
    LOADSLOT(2, u2, av2);
    LOADSLOT(3, u3, av3);
    int i = 0;
    for (; i + 4 < maxd; i += 4) {
        CONSUME(i,     u0, av0); LOADSLOT(i + 4, u0, av0);
        CONSUME(i + 1, u1, av1); LOADSLOT(i + 5, u1, av1);
        CONSUME(i + 2, u2, av2); LOADSLOT(i + 6, u2, av2);
        CONSUME(i + 3, u3, av3); LOADSLOT(i + 7, u3, av3);
    }
    CONSUME(i,     u0, av0);
    CONSUME(i + 1, u1, av1);
    CONSUME(i + 2, u2, av2);
    CONSUME(i + 3, u3, av3);
#undef LOADSLOT
#undef CONSUME

    // each lane of a group already holds the full denom and its 8 features
    float inv = 1.f / dacc;
    const int cb = s * FS + l * 8;           // feature base of this lane
    float v[8];
    #pragma unroll
    for (int j = 0; j < 8; ++j) {
        float t = acc[j] * inv + bias[cb + j];
        v[j] = RELU ? fmaxf(t, 0.f) : t;
    }
    if (BF16OUT) {
        uintx4 pk;
        #pragma unroll
        for (int q = 0; q < 4; ++q)
            pk[q] = (unsigned)f2bf(v[2 * q]) | ((unsigned)f2bf(v[2 * q + 1]) << 16);
        __builtin_nontemporal_store(pk,
            (uintx4*)((unsigned*)out_v + (size_t)node * RU + s * SU + l * 4));
    } else {
        floatx4 o0 = {v[0], v[1], v[2], v[3]};
        floatx4 o1 = {v[4], v[5], v[6], v[7]};
        float* dst = (float*)out_v + (size_t)node * F + cb;
        __builtin_nontemporal_store(o0, (floatx4*)dst);
        __builtin_nontemporal_store(o1, (floatx4*)(dst + 4));
    }
}

// ---------------- host launch ----------------

extern "C" void kernel_launch(void* const* d_in, const int* in_sizes, int n_in,
                              void* d_out, int out_size, void* d_ws, size_t ws_size,
                              hipStream_t stream) {
    const float* x        = (const float*)d_in[0];
    const int*   ei       = (const int*)  d_in[1];
    const float* W1       = (const float*)d_in[2];
    const float* att_src1 = (const float*)d_in[3];
    const float* att_dst1 = (const float*)d_in[4];
    const float* b1       = (const float*)d_in[5];
    const float* W2       = (const float*)d_in[6];
    const float* att_src2 = (const float*)d_in[7];
    const float* att_dst2 = (const float*)d_in[8];
    const float* b2       = (const float*)d_in[9];
    const float* W3       = (const float*)d_in[10];
    const float* att_src3 = (const float*)d_in[11];
    const float* att_dst3 = (const float*)d_in[12];
    const float* b3       = (const float*)d_in[13];

    const int IN_FEATS = 256;
    const int N = in_sizes[0] / IN_FEATS;   // 30000
    const int E = in_sizes[1] / 2;          // 480000
    const int ET = E + N;
    const int NB = (N + 1023) / 1024;       // scan blocks (30)

    // workspace layout
    char* p = (char*)d_ws;
    unsigned short* h_bf    = (unsigned short*)p; p += (size_t)N * 512 * sizeof(unsigned short);
    unsigned short* act_bf  = (unsigned short*)p; p += (size_t)N * 512 * sizeof(unsigned short);
    unsigned short* x_bf    = (unsigned short*)p; p += (size_t)N * 256 * sizeof(unsigned short);
    float*          a_src   = (float*)p;          p += (size_t)N * 4 * sizeof(float);
    float*          a_dst   = (float*)p;          p += (size_t)N * 4 * sizeof(float);
    unsigned short* W1T     = (unsigned short*)p; p += (size_t)512 * 256 * sizeof(unsigned short);
    unsigned short* W2T     = (unsigned short*)p; p += (size_t)512 * 512 * sizeof(unsigned short);
    unsigned short* W3T     = (unsigned short*)p; p += (size_t)128 * 512 * sizeof(unsigned short);
    int*            row_ptr = (int*)p;            p += ((size_t)N + 16) * sizeof(int);
    int*            cursor  = (int*)p;            p += (size_t)N * sizeof(int);
    int*            dhist   = (int*)p;            p += 512 * sizeof(int);
    int*            dcur    = (int*)p;            p += 512 * sizeof(int);
    int*            node_order = (int*)p;         p += (size_t)N * sizeof(int);
    int*            bsum    = (int*)p;            p += 64 * sizeof(int);
    int*            csr_src = (int*)p;            p += (size_t)ET * sizeof(int);

    // ---- prep (x cast + W transposes + hist) + CSR build + degree sort ----
    hipMemsetAsync(cursor, 0, ((size_t)N + 512) * sizeof(int), stream);  // cursor + dhist
    {
        int n4 = N * 256 / 4;
        int total = n4 + 256 * 512 + 512 * 512 + 512 * 128 + E;
        prep_hist_kernel<<<(total + 255) / 256, 256, 0, stream>>>(
            x, x_bf, W1, W1T, W2, W2T, W3, W3T, ei, cursor, n4, E);
    }
    scan_bsum_kernel<<<NB, 1024, 0, stream>>>(cursor, bsum, N);
    scan_final_kernel<<<NB, 1024, 0, stream>>>(cursor, bsum, row_ptr, dhist, N, NB);
    deg_scan_kernel<<<1, 512, 0, stream>>>(dhist, dcur);
    scatter_kernel<<<(E + 2 * N + 255) / 256, 256, 0, stream>>>(
        ei, cursor, csr_src, row_ptr, dcur, node_order, E, N);

    const int MB128 = (N + 127) / 128;      // 235
    const int MB256 = (N + 255) / 256;      // 118
    const int NC32 = (N + 31) / 32;         // node chunks (32 nodes/block)

    // ---- Layer 1: 256 -> 4x128 concat + relu (h bf16) ----
    mfma_gemm_kernel<128, 256><<<dim3(2, MB128), 512, 0, stream>>>(x_bf, W1T, h_bf, att_src1, att_dst1, a_src, a_dst, 4, N, 512, 256);
    agg_kernel<512, 4, 8, true, true><<<8 * NC32, 256, 0, stream>>>((const unsigned*)h_bf, a_src, a_dst, row_ptr, csr_src, node_order, b1, act_bf, N);

    // ---- Layer 2: 512 -> 4x128 concat + relu (h bf16) ----
    mfma_gemm_kernel<128, 256><<<dim3(2, MB128), 512, 0, stream>>>(act_bf, W2T, h_bf, att_src2, att_dst2, a_src, a_dst, 4, N, 512, 512);
    agg_kernel<512, 4, 8, true, true><<<8 * NC32, 256, 0, stream>>>((const unsigned*)h_bf, a_src, a_dst, row_ptr, csr_src, node_order, b2, act_bf, N);

    // ---- Layer 3: 512 -> 1x128 (h bf16), fp32 out, no relu ----
    mfma_gemm_kernel<256, 128><<<dim3(1, MB256), 512, 0, stream>>>(act_bf, W3T, h_bf, att_src3, att_dst3, a_src, a_dst, 1, N, 128, 512);
    agg_kernel<128, 1, 2, false, false><<<2 * NC32, 256, 0, stream>>>((const unsigned*)h_bf, a_src, a_dst, row_ptr, csr_src, node_order, b3, d_out, N);
}